// Round 1
// baseline (717.744 us; speedup 1.0000x reference)
//
#include <hip/hip_runtime.h>
#include <math.h>

#define NN   8192   // nodes
#define KF   512    // in features
#define DF   64     // out features
#define NCH  32     // 8192 / 256 chunks
#define NCOL 130    // 65 dims (64 h1 + 1 ones) * 2 weightings (pos/neg)
#define KC   128    // K-chunk staged in LDS for the GEMM

// ---------------- K0: Wt (transpose of W) and v2 = W^T @ w_att2 ----------------
__global__ void k_prep(const float* __restrict__ W, const float* __restrict__ w2,
                       float* __restrict__ Wt, float* __restrict__ v2) {
    int k = blockIdx.x * 256 + threadIdx.x;
    if (k >= KF) return;
    float a2 = 0.f;
    for (int o = 0; o < DF; ++o) {
        float wv = W[(size_t)o * KF + k];
        Wt[(size_t)k * DF + o] = wv;
        a2 = fmaf(wv, w2[o], a2);
    }
    v2[k] = a2;
}

// ---------------- K1: h1 = x @ W^T  and  s1 = h1 @ w_att1 ----------------
// 4 waves/block, 4 rows/wave -> 16 rows/block, 512 blocks. Wt chunk staged in LDS.
__global__ __launch_bounds__(256) void k_h1s1(const float* __restrict__ x,
        const float* __restrict__ Wt, const float* __restrict__ w_att1,
        float* __restrict__ h1, float* __restrict__ s1) {
    __shared__ float wt[KC * DF]; // 32 KB
    const int tid = threadIdx.x;
    const int wave = tid >> 6, lane = tid & 63;
    const int row0 = blockIdx.x * 16 + wave * 4;
    float acc0 = 0.f, acc1 = 0.f, acc2 = 0.f, acc3 = 0.f;
    for (int kc = 0; kc < KF; kc += KC) {
        __syncthreads();
        const float4* src = reinterpret_cast<const float4*>(Wt + (size_t)kc * DF);
        float4* dst = reinterpret_cast<float4*>(wt);
        #pragma unroll
        for (int t = 0; t < (KC * DF / 4) / 256; ++t) dst[tid + t * 256] = src[tid + t * 256];
        __syncthreads();
        for (int k4 = 0; k4 < KC; k4 += 4) {
            const float w0 = wt[(k4 + 0) * DF + lane];
            const float w1v = wt[(k4 + 1) * DF + lane];
            const float w2v = wt[(k4 + 2) * DF + lane];
            const float w3v = wt[(k4 + 3) * DF + lane];
            const size_t xb = (size_t)row0 * KF + kc + k4;
            float4 x0 = *reinterpret_cast<const float4*>(x + xb);
            float4 x1 = *reinterpret_cast<const float4*>(x + xb + KF);
            float4 x2 = *reinterpret_cast<const float4*>(x + xb + 2 * KF);
            float4 x3 = *reinterpret_cast<const float4*>(x + xb + 3 * KF);
            acc0 = fmaf(x0.x, w0, fmaf(x0.y, w1v, fmaf(x0.z, w2v, fmaf(x0.w, w3v, acc0))));
            acc1 = fmaf(x1.x, w0, fmaf(x1.y, w1v, fmaf(x1.z, w2v, fmaf(x1.w, w3v, acc1))));
            acc2 = fmaf(x2.x, w0, fmaf(x2.y, w1v, fmaf(x2.z, w2v, fmaf(x2.w, w3v, acc2))));
            acc3 = fmaf(x3.x, w0, fmaf(x3.y, w1v, fmaf(x3.z, w2v, fmaf(x3.w, w3v, acc3))));
        }
    }
    const float wa = w_att1[lane];
    float accs[4] = {acc0, acc1, acc2, acc3};
    #pragma unroll
    for (int r = 0; r < 4; ++r) {
        h1[(size_t)(row0 + r) * DF + lane] = accs[r];
        float p = accs[r] * wa;
        #pragma unroll
        for (int off = 32; off; off >>= 1) p += __shfl_xor(p, off);
        if (lane == 0) s1[row0 + r] = p;
    }
}

// ---------------- K2: s2 = n @ v2 (one wave per row) ----------------
__global__ __launch_bounds__(256) void k_s2(const float* __restrict__ n,
        const float* __restrict__ v2, float* __restrict__ s2) {
    const int lane = threadIdx.x & 63;
    const int row = (blockIdx.x * 256 + threadIdx.x) >> 6;
    const float4* a = reinterpret_cast<const float4*>(n + (size_t)row * KF);
    const float4* b = reinterpret_cast<const float4*>(v2);
    float acc = 0.f;
    #pragma unroll
    for (int c = 0; c < 2; ++c) {
        float4 av = a[lane + c * 64], bv = b[lane + c * 64];
        acc = fmaf(av.x, bv.x, fmaf(av.y, bv.y, fmaf(av.z, bv.z, fmaf(av.w, bv.w, acc))));
    }
    #pragma unroll
    for (int off = 32; off; off >>= 1) acc += __shfl_xor(acc, off);
    if (lane == 0) s2[row] = acc;
}

// ---------------- K3: brute-force rank, 2D tiled partial counts ----------------
__global__ __launch_bounds__(256) void k_count(const float* __restrict__ s2,
                                               int* __restrict__ partial) {
    __shared__ float sk[256];
    const int j = blockIdx.x * 256 + threadIdx.x;
    const int k0 = blockIdx.y * 256;
    sk[threadIdx.x] = s2[k0 + threadIdx.x];
    __syncthreads();
    const float mine = s2[j];
    int cnt = 0;
    #pragma unroll 8
    for (int t = 0; t < 256; ++t) {
        float v = sk[t];
        int idx = k0 + t;
        cnt += (v < mine) || (v == mine && idx < j);
    }
    partial[(size_t)blockIdx.y * NN + j] = cnt;
}

// ---------------- K4: reduce ranks + scatter into sorted order, precompute weights ----------------
__global__ __launch_bounds__(256) void k_scatter(const float* __restrict__ s2,
        const int* __restrict__ partial, int* __restrict__ order,
        float* __restrict__ s2s, double* __restrict__ wpos, double* __restrict__ wneg) {
    const int j = blockIdx.x * 256 + threadIdx.x;
    int r = 0;
    for (int kb = 0; kb < NCH; ++kb) r += partial[(size_t)kb * NN + j];
    const float v = s2[j];
    order[r] = j;
    s2s[r] = v;
    wpos[r] = exp((double)v);
    wneg[r] = exp(0.2 * (double)v);
}

// ---------------- K5: per-chunk totals (two-level scan, level 1) ----------------
__global__ __launch_bounds__(256) void k_chunksum(const float* __restrict__ h1,
        const int* __restrict__ order, const double* __restrict__ wpos,
        const double* __restrict__ wneg, double* __restrict__ cT) {
    __shared__ double red[256];
    const int col = blockIdx.x >> 5, c = blockIdx.x & 31;
    const int p = c * 256 + threadIdx.x;
    const double wgt = (col < 65) ? wpos[p] : wneg[p];
    const int d = (col < 65) ? col : col - 65;
    double val = (d < DF) ? wgt * (double)h1[(size_t)order[p] * DF + d] : wgt;
    red[threadIdx.x] = val;
    __syncthreads();
    for (int s = 128; s; s >>= 1) {
        if (threadIdx.x < s) red[threadIdx.x] += red[threadIdx.x + s];
        __syncthreads();
    }
    if (threadIdx.x == 0) cT[blockIdx.x] = red[0];
}

// ---------------- K6: scan the 32 chunk totals per column; write grand totals row ----------------
__global__ void k_chunkscan(const double* __restrict__ cT, double* __restrict__ cO,
                            double* __restrict__ E) {
    const int col = threadIdx.x;
    if (col >= NCOL) return;
    double run = 0.0;
    for (int c = 0; c < NCH; ++c) {
        cO[(size_t)col * NCH + c] = run;
        run += cT[(size_t)col * NCH + c];
    }
    E[(size_t)NN * NCOL + col] = run; // grand total row
}

// ---------------- K7: per-chunk exclusive scan + chunk offset -> E ----------------
__global__ __launch_bounds__(256) void k_scan(const float* __restrict__ h1,
        const int* __restrict__ order, const double* __restrict__ wpos,
        const double* __restrict__ wneg, const double* __restrict__ cO,
        double* __restrict__ E) {
    __shared__ double buf[2][256];
    const int col = blockIdx.x >> 5, c = blockIdx.x & 31;
    const int tid = threadIdx.x;
    const int p = c * 256 + tid;
    const double wgt = (col < 65) ? wpos[p] : wneg[p];
    const int d = (col < 65) ? col : col - 65;
    double val = (d < DF) ? wgt * (double)h1[(size_t)order[p] * DF + d] : wgt;
    buf[0][tid] = val;
    int cur = 0;
    for (int off = 1; off < 256; off <<= 1) {
        __syncthreads();
        double t = buf[cur][tid];
        if (tid >= off) t += buf[cur][tid - off];
        buf[cur ^ 1][tid] = t;
        cur ^= 1;
    }
    __syncthreads();
    const double excl = tid ? buf[cur][tid - 1] : 0.0;
    E[(size_t)p * NCOL + col] = cO[blockIdx.x] + excl;
}

// ---------------- K8: per-row binary search + combine ----------------
__global__ __launch_bounds__(256) void k_out(const float* __restrict__ s1,
        const float* __restrict__ s2s, const double* __restrict__ E,
        float* __restrict__ out) {
    const int lane = threadIdx.x & 63, wave = threadIdx.x >> 6;
    const int i = blockIdx.x * 4 + wave;
    const float s1v = s1[i];
    const float t = -s1v;
    int lo = 0, hi = NN;
    while (lo < hi) {
        int mid = (lo + hi) >> 1;
        if (s2s[mid] < t) lo = mid + 1; else hi = mid;
    }
    const double* Ek = E + (size_t)lo * NCOL;
    const double* Et = E + (size_t)NN * NCOL;
    const double e1 = exp((double)s1v);
    const double e2 = exp(0.2 * (double)s1v);
    const double num = e1 * (Et[lane] - Ek[lane]) + e2 * Ek[65 + lane];
    const double den = e1 * (Et[DF] - Ek[DF]) + e2 * Ek[65 + DF];
    out[(size_t)i * DF + lane] = (float)(num / den);
}

extern "C" void kernel_launch(void* const* d_in, const int* in_sizes, int n_in,
                              void* d_out, int out_size, void* d_ws, size_t ws_size,
                              hipStream_t stream) {
    const float* x  = (const float*)d_in[0];
    const float* nmat = (const float*)d_in[1];
    const float* W  = (const float*)d_in[2];
    const float* w1 = (const float*)d_in[3];
    const float* w2 = (const float*)d_in[4];
    float* out = (float*)d_out;

    char* ws = (char*)d_ws;
    size_t off = 0;
    auto alloc = [&](size_t bytes) -> void* {
        void* p = ws + off;
        off += (bytes + 15) & ~(size_t)15;
        return p;
    };
    float*  Wt      = (float*)alloc((size_t)KF * DF * 4);     // 128 KB
    float*  v2      = (float*)alloc((size_t)KF * 4);
    float*  h1      = (float*)alloc((size_t)NN * DF * 4);     // 2 MB
    float*  s1      = (float*)alloc((size_t)NN * 4);
    float*  s2      = (float*)alloc((size_t)NN * 4);
    int*    partial = (int*)alloc((size_t)NCH * NN * 4);      // 1 MB
    int*    order   = (int*)alloc((size_t)NN * 4);
    float*  s2s     = (float*)alloc((size_t)NN * 4);
    double* wpos    = (double*)alloc((size_t)NN * 8);
    double* wneg    = (double*)alloc((size_t)NN * 8);
    double* cT      = (double*)alloc((size_t)NCOL * NCH * 8);
    double* cO      = (double*)alloc((size_t)NCOL * NCH * 8);
    double* E       = (double*)alloc((size_t)(NN + 1) * NCOL * 8); // 8.5 MB

    k_prep<<<2, 256, 0, stream>>>(W, w2, Wt, v2);
    k_h1s1<<<512, 256, 0, stream>>>(x, Wt, w1, h1, s1);
    k_s2<<<NN / 4, 256, 0, stream>>>(nmat, v2, s2);
    k_count<<<dim3(NCH, NCH), 256, 0, stream>>>(s2, partial);
    k_scatter<<<NCH, 256, 0, stream>>>(s2, partial, order, s2s, wpos, wneg);
    k_chunksum<<<NCOL * NCH, 256, 0, stream>>>(h1, order, wpos, wneg, cT);
    k_chunkscan<<<1, 256, 0, stream>>>(cT, cO, E);
    k_scan<<<NCOL * NCH, 256, 0, stream>>>(h1, order, wpos, wneg, cO, E);
    k_out<<<NN / 4, 256, 0, stream>>>(s1, s2s, E, out);
}

// Round 2
// 76.603 us; speedup vs baseline: 9.3696x; 9.3696x over previous
//
#include <hip/hip_runtime.h>
#include <math.h>

#define NN   8192   // nodes
#define KF   512    // in features
#define DF   64     // out features
#define NCH  32     // 8192 / 256 chunks
#define NCOL 130    // 65 dims (64 h1 + 1 ones) * 2 weightings (pos/neg)

#define BM     64   // rows per GEMM block
#define BK     32   // K-chunk staged in LDS
#define KSPLIT 4    // split-K factor

// ---------------- K0: Wt (transpose of W) and v2 = W^T @ w_att2 ----------------
__global__ void k_prep(const float* __restrict__ W, const float* __restrict__ w2,
                       float* __restrict__ Wt, float* __restrict__ v2) {
    int k = blockIdx.x * 256 + threadIdx.x;
    if (k >= KF) return;
    float a2 = 0.f;
    for (int o = 0; o < DF; ++o) {
        float wv = W[(size_t)o * KF + k];
        Wt[(size_t)k * DF + o] = wv;
        a2 = fmaf(wv, w2[o], a2);
    }
    v2[k] = a2;
}

// ---------------- K1: hpart[s] = x[:, Ks] @ Wt[Ks, :]  (register-tiled, split-K) ----------------
// grid (NN/BM, KSPLIT), 256 threads = 16x16, each thread owns a 4x4 output subtile.
__global__ __launch_bounds__(256, 2) void k_gemm(const float* __restrict__ x,
        const float* __restrict__ Wt, float* __restrict__ hpart) {
    __shared__ alignas(16) float xs[BK][BM + 4];  // transposed x tile; stride 68 floats = 272B (16B mult)
    __shared__ alignas(16) float wts[BK][DF];
    const int tid = threadIdx.x;
    const int ty = tid >> 4, tx = tid & 15;
    const int row0 = blockIdx.x * BM;
    const int kbase = blockIdx.y * (KF / KSPLIT);

    float acc[4][4] = {};
    for (int kc = 0; kc < KF / KSPLIT; kc += BK) {
        const int kk = kbase + kc;
        // stage x tile (64 rows x 32 k), transposed into LDS
        {
            const int r  = tid >> 3;        // 0..31
            const int c4 = (tid & 7) * 4;   // 0..28
            float4 v0 = *reinterpret_cast<const float4*>(x + (size_t)(row0 + r) * KF + kk + c4);
            float4 v1 = *reinterpret_cast<const float4*>(x + (size_t)(row0 + 32 + r) * KF + kk + c4);
            xs[c4 + 0][r] = v0.x; xs[c4 + 1][r] = v0.y; xs[c4 + 2][r] = v0.z; xs[c4 + 3][r] = v0.w;
            xs[c4 + 0][32 + r] = v1.x; xs[c4 + 1][32 + r] = v1.y; xs[c4 + 2][32 + r] = v1.z; xs[c4 + 3][32 + r] = v1.w;
            // stage Wt tile (32 k x 64 cols), contiguous copy
            const float4* src = reinterpret_cast<const float4*>(Wt + (size_t)kk * DF);
            float4* dst = reinterpret_cast<float4*>(&wts[0][0]);
            dst[tid] = src[tid];
            dst[tid + 256] = src[tid + 256];
        }
        __syncthreads();
        #pragma unroll 8
        for (int k = 0; k < BK; ++k) {
            float4 a4 = *reinterpret_cast<const float4*>(&xs[k][ty * 4]);
            float4 b4 = *reinterpret_cast<const float4*>(&wts[k][tx * 4]);
            const float av[4] = {a4.x, a4.y, a4.z, a4.w};
            const float bv[4] = {b4.x, b4.y, b4.z, b4.w};
            #pragma unroll
            for (int i = 0; i < 4; ++i)
                #pragma unroll
                for (int j = 0; j < 4; ++j)
                    acc[i][j] = fmaf(av[i], bv[j], acc[i][j]);
        }
        __syncthreads();
    }
    float* hp = hpart + (size_t)blockIdx.y * NN * DF;
    #pragma unroll
    for (int i = 0; i < 4; ++i)
        *reinterpret_cast<float4*>(hp + (size_t)(row0 + ty * 4 + i) * DF + tx * 4) =
            make_float4(acc[i][0], acc[i][1], acc[i][2], acc[i][3]);
}

// ---------------- K1b: h1 = sum_s hpart[s]; s1 = h1 @ w_att1 ----------------
__global__ __launch_bounds__(256) void k_combine(const float* __restrict__ hpart,
        const float* __restrict__ w_att1, float* __restrict__ h1, float* __restrict__ s1) {
    const int lane = threadIdx.x & 63, wave = threadIdx.x >> 6;
    const int row = blockIdx.x * 4 + wave;
    float v = 0.f;
    #pragma unroll
    for (int s = 0; s < KSPLIT; ++s) v += hpart[((size_t)s * NN + row) * DF + lane];
    h1[(size_t)row * DF + lane] = v;
    float p = v * w_att1[lane];
    #pragma unroll
    for (int off = 32; off; off >>= 1) p += __shfl_xor(p, off);
    if (lane == 0) s1[row] = p;
}

// ---------------- K2: s2 = n @ v2 (one wave per row) ----------------
__global__ __launch_bounds__(256) void k_s2(const float* __restrict__ n,
        const float* __restrict__ v2, float* __restrict__ s2) {
    const int lane = threadIdx.x & 63;
    const int row = (blockIdx.x * 256 + threadIdx.x) >> 6;
    const float4* a = reinterpret_cast<const float4*>(n + (size_t)row * KF);
    const float4* b = reinterpret_cast<const float4*>(v2);
    float acc = 0.f;
    #pragma unroll
    for (int c = 0; c < 2; ++c) {
        float4 av = a[lane + c * 64], bv = b[lane + c * 64];
        acc = fmaf(av.x, bv.x, fmaf(av.y, bv.y, fmaf(av.z, bv.z, fmaf(av.w, bv.w, acc))));
    }
    #pragma unroll
    for (int off = 32; off; off >>= 1) acc += __shfl_xor(acc, off);
    if (lane == 0) s2[row] = acc;
}

// ---------------- K3: brute-force rank, 2D tiled partial counts ----------------
__global__ __launch_bounds__(256) void k_count(const float* __restrict__ s2,
                                               int* __restrict__ partial) {
    __shared__ float sk[256];
    const int j = blockIdx.x * 256 + threadIdx.x;
    const int k0 = blockIdx.y * 256;
    sk[threadIdx.x] = s2[k0 + threadIdx.x];
    __syncthreads();
    const float mine = s2[j];
    int cnt = 0;
    #pragma unroll 8
    for (int t = 0; t < 256; ++t) {
        float v = sk[t];
        int idx = k0 + t;
        cnt += (v < mine) || (v == mine && idx < j);
    }
    partial[(size_t)blockIdx.y * NN + j] = cnt;
}

// ---------------- K4: reduce ranks + scatter into sorted order, precompute weights ----------------
__global__ __launch_bounds__(256) void k_scatter(const float* __restrict__ s2,
        const int* __restrict__ partial, int* __restrict__ order,
        float* __restrict__ s2s, double* __restrict__ wpos, double* __restrict__ wneg) {
    const int j = blockIdx.x * 256 + threadIdx.x;
    int r = 0;
    for (int kb = 0; kb < NCH; ++kb) r += partial[(size_t)kb * NN + j];
    const float v = s2[j];
    order[r] = j;
    s2s[r] = v;
    wpos[r] = exp((double)v);
    wneg[r] = exp(0.2 * (double)v);
}

// ---------------- K5: per-chunk totals (two-level scan, level 1) ----------------
__global__ __launch_bounds__(256) void k_chunksum(const float* __restrict__ h1,
        const int* __restrict__ order, const double* __restrict__ wpos,
        const double* __restrict__ wneg, double* __restrict__ cT) {
    __shared__ double red[256];
    const int col = blockIdx.x >> 5, c = blockIdx.x & 31;
    const int p = c * 256 + threadIdx.x;
    const double wgt = (col < 65) ? wpos[p] : wneg[p];
    const int d = (col < 65) ? col : col - 65;
    double val = (d < DF) ? wgt * (double)h1[(size_t)order[p] * DF + d] : wgt;
    red[threadIdx.x] = val;
    __syncthreads();
    for (int s = 128; s; s >>= 1) {
        if (threadIdx.x < s) red[threadIdx.x] += red[threadIdx.x + s];
        __syncthreads();
    }
    if (threadIdx.x == 0) cT[blockIdx.x] = red[0];
}

// ---------------- K6: scan the 32 chunk totals per column; write grand totals row ----------------
__global__ void k_chunkscan(const double* __restrict__ cT, double* __restrict__ cO,
                            double* __restrict__ E) {
    const int col = threadIdx.x;
    if (col >= NCOL) return;
    double run = 0.0;
    for (int c = 0; c < NCH; ++c) {
        cO[(size_t)col * NCH + c] = run;
        run += cT[(size_t)col * NCH + c];
    }
    E[(size_t)NN * NCOL + col] = run; // grand total row
}

// ---------------- K7: per-chunk exclusive scan + chunk offset -> E ----------------
__global__ __launch_bounds__(256) void k_scan(const float* __restrict__ h1,
        const int* __restrict__ order, const double* __restrict__ wpos,
        const double* __restrict__ wneg, const double* __restrict__ cO,
        double* __restrict__ E) {
    __shared__ double buf[2][256];
    const int col = blockIdx.x >> 5, c = blockIdx.x & 31;
    const int tid = threadIdx.x;
    const int p = c * 256 + tid;
    const double wgt = (col < 65) ? wpos[p] : wneg[p];
    const int d = (col < 65) ? col : col - 65;
    double val = (d < DF) ? wgt * (double)h1[(size_t)order[p] * DF + d] : wgt;
    buf[0][tid] = val;
    int cur = 0;
    for (int off = 1; off < 256; off <<= 1) {
        __syncthreads();
        double t = buf[cur][tid];
        if (tid >= off) t += buf[cur][tid - off];
        buf[cur ^ 1][tid] = t;
        cur ^= 1;
    }
    __syncthreads();
    const double excl = tid ? buf[cur][tid - 1] : 0.0;
    E[(size_t)p * NCOL + col] = cO[blockIdx.x] + excl;
}

// ---------------- K8: per-row binary search + combine ----------------
__global__ __launch_bounds__(256) void k_out(const float* __restrict__ s1,
        const float* __restrict__ s2s, const double* __restrict__ E,
        float* __restrict__ out) {
    const int lane = threadIdx.x & 63, wave = threadIdx.x >> 6;
    const int i = blockIdx.x * 4 + wave;
    const float s1v = s1[i];
    const float t = -s1v;
    int lo = 0, hi = NN;
    while (lo < hi) {
        int mid = (lo + hi) >> 1;
        if (s2s[mid] < t) lo = mid + 1; else hi = mid;
    }
    const double* Ek = E + (size_t)lo * NCOL;
    const double* Et = E + (size_t)NN * NCOL;
    const double e1 = exp((double)s1v);
    const double e2 = exp(0.2 * (double)s1v);
    const double num = e1 * (Et[lane] - Ek[lane]) + e2 * Ek[65 + lane];
    const double den = e1 * (Et[DF] - Ek[DF]) + e2 * Ek[65 + DF];
    out[(size_t)i * DF + lane] = (float)(num / den);
}

extern "C" void kernel_launch(void* const* d_in, const int* in_sizes, int n_in,
                              void* d_out, int out_size, void* d_ws, size_t ws_size,
                              hipStream_t stream) {
    const float* x  = (const float*)d_in[0];
    const float* nmat = (const float*)d_in[1];
    const float* W  = (const float*)d_in[2];
    const float* w1 = (const float*)d_in[3];
    const float* w2 = (const float*)d_in[4];
    float* out = (float*)d_out;

    char* ws = (char*)d_ws;
    size_t off = 0;
    auto alloc = [&](size_t bytes) -> void* {
        void* p = ws + off;
        off += (bytes + 255) & ~(size_t)255;
        return p;
    };
    float*  Wt      = (float*)alloc((size_t)KF * DF * 4);     // 128 KB
    float*  v2      = (float*)alloc((size_t)KF * 4);
    float*  h1      = (float*)alloc((size_t)NN * DF * 4);     // 2 MB
    float*  s1      = (float*)alloc((size_t)NN * 4);
    float*  s2      = (float*)alloc((size_t)NN * 4);
    int*    partial = (int*)alloc((size_t)NCH * NN * 4);      // 1 MB
    int*    order   = (int*)alloc((size_t)NN * 4);
    float*  s2s     = (float*)alloc((size_t)NN * 4);
    double* wpos    = (double*)alloc((size_t)NN * 8);
    double* wneg    = (double*)alloc((size_t)NN * 8);
    double* cT      = (double*)alloc((size_t)NCOL * NCH * 8);
    double* cO      = (double*)alloc((size_t)NCOL * NCH * 8);
    double* E       = (double*)alloc((size_t)(NN + 1) * NCOL * 8); // 8.5 MB
    // hpart (KSPLIT * NN * DF * 4 = 8 MB) aliases E: hpart is dead before the
    // first write to E (k_chunkscan), and E is not read before that.
    float*  hpart   = (float*)E;

    k_prep<<<2, 256, 0, stream>>>(W, w2, Wt, v2);
    k_gemm<<<dim3(NN / BM, KSPLIT), 256, 0, stream>>>(x, Wt, hpart);
    k_combine<<<NN / 4, 256, 0, stream>>>(hpart, w1, h1, s1);
    k_s2<<<NN / 4, 256, 0, stream>>>(nmat, v2, s2);
    k_count<<<dim3(NCH, NCH), 256, 0, stream>>>(s2, partial);
    k_scatter<<<NCH, 256, 0, stream>>>(s2, partial, order, s2s, wpos, wneg);
    k_chunksum<<<NCOL * NCH, 256, 0, stream>>>(h1, order, wpos, wneg, cT);
    k_chunkscan<<<1, 256, 0, stream>>>(cT, cO, E);
    k_scan<<<NCOL * NCH, 256, 0, stream>>>(h1, order, wpos, wneg, cO, E);
    k_out<<<NN / 4, 256, 0, stream>>>(s1, s2s, E, out);
}